// Round 30
// baseline (110.939 us; speedup 1.0000x reference)
//
#include <hip/hip_runtime.h>

// GATConv: N=50000, NIN=128, H=4, C=16 (HC=64), E=800000 (+N self-loops,
// synthesized inside k_gat). Slot-table aggregation (no CSR).
// k_fused (r29): scatter blocks [0,2048) + xw MFMA blocks [2048,5173) in one
// dispatch — xw hides inside scatter's latency bubbles. k_gat (r30): each wave
// owns UD=4 consecutive dsts SEQUENTIALLY with next-dst prefetch — amortizes
// the ~1500cy per-dst prologue chain (cnt->a_dst->a_src->exp) that was ~1/3
// of wave lifetime at 1 dst/wave. (Interleaved multi-dst failed in r12/r21
// via VGPR blowup; sequential+prefetch costs ~6 regs.)
#define NN 50000
#define NIN 128
#define NH 4
#define NC 16
#define HC 64
#define NE 800000
#define NEG_SLOPE 0.2f
#define RPB 16                       // rows per block in xw path
#define XWB (NN / RPB)               // 3125 xw blocks
#define NPART 8                      // dst partitions (== XCD count)
#define SCHUNK 256                   // blocks per partition in scatter path
#define SBLK (NPART * SCHUNK)        // 2048 scatter blocks (dispatched first)
#define DPP (NN / NPART)             // 6250 dst per partition
#define UD 4                         // dsts per wave in k_gat
#define GPB ((DPP + 4 * UD - 1) / (4 * UD))  // 391 gat blocks per partition
#define CAP 32                       // slots per destination
#define OFCAP 8192                   // overflow list capacity (safety margin)

typedef __attribute__((ext_vector_type(8))) __bf16 bf16x8;
typedef __attribute__((ext_vector_type(4))) float f32x4;

__device__ __forceinline__ ushort f2bf(float v) {  // RNE f32->bf16
  unsigned u = __float_as_uint(v);
  return (ushort)((u + 0x7FFFu + ((u >> 16) & 1u)) >> 16);
}
__device__ __forceinline__ float bf2f(ushort b) {
  return __uint_as_float((unsigned)b << 16);
}
__device__ __forceinline__ float lrelu_exp(float e) {
  e = e > 0.f ? e : NEG_SLOPE * e;
  return __expf(fminf(e, 60.f));  // no max-shift needed: |e|<~12 on this data
}

// Fused producer kernel. Blocks [0,SBLK): dst-partitioned slot scatter
// (d-stream + lazy s load + cursor atomic + 2B store; XCD-affine via b&7).
// Blocks [SBLK, SBLK+XWB): xw(bf16) = x @ W via MFMA (wave w = head w,
// 4x mfma_f32_16x16x32_bf16 over K=128) + attention dots.
// Paths touch disjoint buffers -> race-free.
__global__ __launch_bounds__(256, 4) void k_fused(
    const float* __restrict__ x, const float* __restrict__ W,
    const float* __restrict__ att_src, const float* __restrict__ att_dst,
    ushort* __restrict__ xwb, float* __restrict__ a_src, float* __restrict__ a_dst,
    int* __restrict__ cnt, int* __restrict__ ofcnt,
    const int* __restrict__ ei,
    ushort* __restrict__ ss_slot, unsigned* __restrict__ of) {
  __shared__ ushort Wt[HC][NIN + 8];   // W transposed, bf16: 17.4 KB
  __shared__ ushort xs[RPB][NIN + 8];  // x tile, bf16: 4.4 KB
  int tid = threadIdx.x;

  if (blockIdx.x < SBLK) {
    // ---- scatter path (no LDS, no barriers) ----
    int p = blockIdx.x & (NPART - 1);
    int chunk = blockIdx.x >> 3;  // 0..SCHUNK-1
    int dlo = p * DPP, dhi = dlo + DPP;
    const int4* d4p = (const int4*)(ei + NE);
    const int ngroups = NE / 4;  // 200000
    for (int g = chunk * 256 + tid; g < ngroups; g += SCHUNK * 256) {
      int4 d4 = d4p[g];
#pragma unroll
      for (int c = 0; c < 4; ++c) {
        int d = (c == 0) ? d4.x : (c == 1) ? d4.y : (c == 2) ? d4.z : d4.w;
        if (d >= dlo && d < dhi) {
          int s = ei[g * 4 + c];  // lazy src load (L2/L3; hidden by atomic)
          int pos = atomicAdd(&cnt[d], 1);
          if (pos < CAP) {
            ss_slot[d * CAP + pos] = (ushort)s;
          } else {
            int op = atomicAdd(ofcnt, 1);
            if (op < OFCAP) of[op] = (unsigned)s | ((unsigned)d << 16);
          }
        }
      }
    }
    return;
  }

  // ---- xw path ----
  int bid = blockIdx.x - SBLK;
  int row0 = bid * RPB;  // NN % RPB == 0
  for (int i = tid; i < NIN * HC; i += 256) {
    int k = i >> 6, c = i & 63;
    Wt[c][k] = f2bf(W[i]);
  }
  {
    int f = tid * 8;  // 256*8 == 16*128
    int r = f >> 7, k = f & 127;
    const float4* xp = (const float4*)(x + (size_t)row0 * NIN + f);
    float4 v0 = xp[0], v1 = xp[1];
    union { bf16x8 v; ushort u[8]; } pkd;
    pkd.u[0] = f2bf(v0.x); pkd.u[1] = f2bf(v0.y);
    pkd.u[2] = f2bf(v0.z); pkd.u[3] = f2bf(v0.w);
    pkd.u[4] = f2bf(v1.x); pkd.u[5] = f2bf(v1.y);
    pkd.u[6] = f2bf(v1.z); pkd.u[7] = f2bf(v1.w);
    *(bf16x8*)&xs[r][k] = pkd.v;
  }
  __syncthreads();
  int l = tid & 63, w = tid >> 6;   // wave w == head w
  int arow = l & 15;                // A row / B col within tile
  int koff = (l >> 4) * 8;          // k sub-offset for A and B fragments
  f32x4 acc = {0.f, 0.f, 0.f, 0.f};
#pragma unroll
  for (int kt = 0; kt < 4; ++kt) {
    bf16x8 av = *(const bf16x8*)&xs[arow][kt * 32 + koff];
    bf16x8 bv = *(const bf16x8*)&Wt[w * 16 + arow][kt * 32 + koff];
    acc = __builtin_amdgcn_mfma_f32_16x16x32_bf16(av, bv, acc, 0, 0, 0);
  }
  int col = l & 15;
  int rgrp = l >> 4;
  float as_ = att_src[w * NC + col], ad_ = att_dst[w * NC + col];
#pragma unroll
  for (int q = 0; q < 4; ++q) {
    int gr = row0 + rgrp * 4 + q;
    float v = acc[q];
    xwb[(size_t)gr * HC + w * 16 + col] = f2bf(v);
    float ps = v * as_, pd = v * ad_;
#pragma unroll
    for (int off = 8; off >= 1; off >>= 1) {
      ps += __shfl_xor(ps, off, 64);
      pd += __shfl_xor(pd, off, 64);
    }
    if (col == 0) {
      a_src[gr * NH + w] = ps;
      a_dst[gr * NH + w] = pd;
    }
  }
}

// k_gat: each wave owns UD=4 CONSECUTIVE dsts, processed sequentially; the
// next dst's cnt/a_dst/a_src loads issue before the current dst's block loop
// (prologue chain hidden under pipelined gathers). Per-dst body = r28's
// measured-optimal 16-lane-broadcast form. XCD-affine mapping (NPART=8).
// Lane layout head-major: lane j = head (j>>4) x slot (j&15).
__global__ __launch_bounds__(256) void k_gat(
    const int* __restrict__ cnt, const ushort* __restrict__ ss_slot,
    const int* __restrict__ ofcnt, const unsigned* __restrict__ of,
    const float* __restrict__ a_src, const float* __restrict__ a_dst,
    const ushort* __restrict__ xwb, const float* __restrict__ bias,
    float* __restrict__ out) {
  int tid = threadIdx.x;
  int wv = tid >> 6, j = tid & 63;
  int p = blockIdx.x & (NPART - 1);
  int idx = blockIdx.x >> 3;  // 0..GPB-1
  int dd0 = idx * (4 * UD) + wv * UD;  // this wave's first dst offset
  if (dd0 >= DPP) return;
  int h = j >> 4, sl = j & 15;
  float bj = bias[j];
  int oc = min(*ofcnt, OFCAP);

  // prefetch state for first dst
  int dN = p * DPP + dd0;
  int degN = min(cnt[dN], CAP);
  float adrN = a_dst[(size_t)dN * NH + h];
  float asN = a_src[(size_t)dN * NH + h];

  for (int u = 0; u < UD; ++u) {
    int dd = dd0 + u;
    if (dd >= DPP) break;
    int d = p * DPP + dd;
    int deg = degN;
    float adr = adrN;
    float as0 = asN;
    // issue next dst's prologue loads NOW (hidden under this dst's gathers)
    if (u + 1 < UD && dd + 1 < DPP) {
      int dn = d + 1;
      degN = min(cnt[dn], CAP);
      adrN = a_dst[(size_t)dn * NH + h];
      asN = a_src[(size_t)dn * NH + h];
    }
    int base = d * CAP;
    float ws = lrelu_exp(as0 + adr);             // self score
    float lsum = (sl == 0) ? ws : 0.f;           // per-lane partial denom
    float acc = ws * bf2f(xwb[(size_t)d * HC + j]);  // self contribution

    for (int i0 = 0; i0 < deg; i0 += 16) {
      int nb = min(16, deg - i0);
      int s_j = 0;
      float al = 0.f;
      if (sl < nb) {
        s_j = (int)ss_slot[base + i0 + sl];                 // coalesced 2B
        al = lrelu_exp(a_src[(size_t)s_j * NH + h] + adr);  // L2-resident
      }
      lsum += al;
      if (nb == 16) {
#pragma unroll
        for (int k = 0; k < 16; ++k) {
          int s = __builtin_amdgcn_readlane(s_j, k);  // lane k holds slot k
          float alpha = __shfl(al, k, 16);
          acc += alpha * bf2f(xwb[(size_t)s * HC + j]);
        }
      } else {
        for (int k = 0; k < nb; ++k) {
          int s = __shfl(s_j, k, 16);
          float alpha = __shfl(al, k, 16);
          acc += alpha * bf2f(xwb[(size_t)s * HC + j]);
        }
      }
    }
    // overflow replay (tiny; all-lane cached reads, match on d)
    for (int e = 0; e < oc; ++e) {
      unsigned r = of[e];
      if ((int)(r >> 16) == d) {
        int s = (int)(r & 0xFFFFu);
        float al = lrelu_exp(a_src[(size_t)s * NH + h] + adr);
        if (sl == 0) lsum += al;
        acc += al * bf2f(xwb[(size_t)s * HC + j]);
      }
    }
    float L = lsum;
#pragma unroll
    for (int off = 8; off >= 1; off >>= 1) L += __shfl_xor(L, off, 64);
    out[(size_t)d * HC + j] = acc / (L + 1e-16f) + bj;
  }
}

extern "C" void kernel_launch(void* const* d_in, const int* in_sizes, int n_in,
                              void* d_out, int out_size, void* d_ws, size_t ws_size,
                              hipStream_t stream) {
  const float* x       = (const float*)d_in[0];
  const int*   ei      = (const int*)d_in[1];
  // d_in[2] = edge_attr: ignored by the reference layer
  const float* W       = (const float*)d_in[3];
  const float* att_src = (const float*)d_in[4];
  const float* att_dst = (const float*)d_in[5];
  const float* bias    = (const float*)d_in[6];
  float* out = (float*)d_out;

  char* p = (char*)d_ws;
  ushort*   xwb     = (ushort*)p;   p += (size_t)NN * HC * 2;    // 6.4 MB
  float*    a_src   = (float*)p;    p += (size_t)NN * NH * 4;    // 0.8 MB
  float*    a_dst   = (float*)p;    p += (size_t)NN * NH * 4;    // 0.8 MB
  int*      cnt     = (int*)p;      p += (size_t)NN * 4;         // 0.2 MB
  int*      ofcnt   = (int*)p;      p += 64;                     // 1 + pad
  ushort*   ss_slot = (ushort*)p;   p += (size_t)NN * CAP * 2;   // 3.2 MB
  unsigned* of      = (unsigned*)p; p += (size_t)OFCAP * 4;      // 32 KB

  hipMemsetAsync(cnt, 0, (size_t)NN * 4 + 64, stream);  // cnt + ofcnt
  k_fused<<<SBLK + XWB, 256, 0, stream>>>(x, W, att_src, att_dst,
                                          xwb, a_src, a_dst, cnt, ofcnt,
                                          ei, ss_slot, of);
  k_gat<<<NPART * GPB, 256, 0, stream>>>(cnt, ss_slot, ofcnt, of,
                                         a_src, a_dst, xwb, bias, out);
}

// Round 31
// 102.606 us; speedup vs baseline: 1.0812x; 1.0812x over previous
//
#include <hip/hip_runtime.h>

// GATConv: N=50000, NIN=128, H=4, C=16 (HC=64), E=800000 (+N self-loops,
// synthesized inside k_gat). Slot-table aggregation (no CSR).
// FINAL (r29 configuration, measured optimum 103.7us over 30 rounds):
//  - k_fused: scatter blocks [0,2048) (latency-bound) + xw MFMA blocks
//    [2048,5173) (compute-bound) in one dispatch — xw hides in scatter's
//    latency bubbles; edge pack pass deleted (d-stream + lazy s load).
//  - k_gat: one dst per wave, 16-lane-broadcast body — measured optimum
//    among 8 structural variants (dual-dst r12, chunk-48 r9, depth-2 r21,
//    scr-precompute r13-15, int8 r23, wave-uniform r27, UD-prefetch r30
//    all regressed: TLP is k_gat's only latency hider; don't trade it).
//  - Ledger: 3466us (r1) -> 103.7us (r29), 33.4x.
#define NN 50000
#define NIN 128
#define NH 4
#define NC 16
#define HC 64
#define NE 800000
#define NEG_SLOPE 0.2f
#define RPB 16                       // rows per block in xw path
#define XWB (NN / RPB)               // 3125 xw blocks
#define NPART 8                      // dst partitions (== XCD count)
#define SCHUNK 256                   // blocks per partition in scatter path
#define SBLK (NPART * SCHUNK)        // 2048 scatter blocks (dispatched first)
#define DPP (NN / NPART)             // 6250 dst per partition
#define GPB 1563                     // gat blocks per partition = ceil(6250/4)
#define CAP 32                       // slots per destination
#define OFCAP 8192                   // overflow list capacity (safety margin)

typedef __attribute__((ext_vector_type(8))) __bf16 bf16x8;
typedef __attribute__((ext_vector_type(4))) float f32x4;

__device__ __forceinline__ ushort f2bf(float v) {  // RNE f32->bf16
  unsigned u = __float_as_uint(v);
  return (ushort)((u + 0x7FFFu + ((u >> 16) & 1u)) >> 16);
}
__device__ __forceinline__ float bf2f(ushort b) {
  return __uint_as_float((unsigned)b << 16);
}
__device__ __forceinline__ float lrelu_exp(float e) {
  e = e > 0.f ? e : NEG_SLOPE * e;
  return __expf(fminf(e, 60.f));  // no max-shift needed: |e|<~12 on this data
}

// Fused producer kernel. Blocks [0,SBLK): dst-partitioned slot scatter
// (d-stream + lazy s load + cursor atomic + 2B store; XCD-affine via b&7).
// Blocks [SBLK, SBLK+XWB): xw(bf16) = x @ W via MFMA (wave w = head w,
// 4x mfma_f32_16x16x32_bf16 over K=128) + attention dots.
// Paths touch disjoint buffers -> race-free; LDS 22KB caps 7 blocks/CU.
__global__ __launch_bounds__(256, 4) void k_fused(
    const float* __restrict__ x, const float* __restrict__ W,
    const float* __restrict__ att_src, const float* __restrict__ att_dst,
    ushort* __restrict__ xwb, float* __restrict__ a_src, float* __restrict__ a_dst,
    int* __restrict__ cnt, int* __restrict__ ofcnt,
    const int* __restrict__ ei,
    ushort* __restrict__ ss_slot, unsigned* __restrict__ of) {
  __shared__ ushort Wt[HC][NIN + 8];   // W transposed, bf16: 17.4 KB
  __shared__ ushort xs[RPB][NIN + 8];  // x tile, bf16: 4.4 KB
  int tid = threadIdx.x;

  if (blockIdx.x < SBLK) {
    // ---- scatter path (no LDS, no barriers) ----
    int p = blockIdx.x & (NPART - 1);
    int chunk = blockIdx.x >> 3;  // 0..SCHUNK-1
    int dlo = p * DPP, dhi = dlo + DPP;
    const int4* d4p = (const int4*)(ei + NE);
    const int ngroups = NE / 4;  // 200000
    for (int g = chunk * 256 + tid; g < ngroups; g += SCHUNK * 256) {
      int4 d4 = d4p[g];
#pragma unroll
      for (int c = 0; c < 4; ++c) {
        int d = (c == 0) ? d4.x : (c == 1) ? d4.y : (c == 2) ? d4.z : d4.w;
        if (d >= dlo && d < dhi) {
          int s = ei[g * 4 + c];  // lazy src load (L2/L3; hidden by atomic)
          int pos = atomicAdd(&cnt[d], 1);
          if (pos < CAP) {
            ss_slot[d * CAP + pos] = (ushort)s;
          } else {
            int op = atomicAdd(ofcnt, 1);
            if (op < OFCAP) of[op] = (unsigned)s | ((unsigned)d << 16);
          }
        }
      }
    }
    return;
  }

  // ---- xw path ----
  int bid = blockIdx.x - SBLK;
  int row0 = bid * RPB;  // NN % RPB == 0
  // stage W^T (coalesced global read, scattered 2B LDS writes, one-time)
  for (int i = tid; i < NIN * HC; i += 256) {
    int k = i >> 6, c = i & 63;
    Wt[c][k] = f2bf(W[i]);
  }
  // stage x tile: thread t converts 8 consecutive floats -> one b128 store
  {
    int f = tid * 8;  // 256*8 == 16*128
    int r = f >> 7, k = f & 127;
    const float4* xp = (const float4*)(x + (size_t)row0 * NIN + f);
    float4 v0 = xp[0], v1 = xp[1];
    union { bf16x8 v; ushort u[8]; } pkd;
    pkd.u[0] = f2bf(v0.x); pkd.u[1] = f2bf(v0.y);
    pkd.u[2] = f2bf(v0.z); pkd.u[3] = f2bf(v0.w);
    pkd.u[4] = f2bf(v1.x); pkd.u[5] = f2bf(v1.y);
    pkd.u[6] = f2bf(v1.z); pkd.u[7] = f2bf(v1.w);
    *(bf16x8*)&xs[r][k] = pkd.v;
  }
  __syncthreads();
  int l = tid & 63, w = tid >> 6;   // wave w == head w
  int arow = l & 15;                // A row / B col within tile
  int koff = (l >> 4) * 8;          // k sub-offset for A and B fragments
  f32x4 acc = {0.f, 0.f, 0.f, 0.f};
#pragma unroll
  for (int kt = 0; kt < 4; ++kt) {
    bf16x8 av = *(const bf16x8*)&xs[arow][kt * 32 + koff];
    bf16x8 bv = *(const bf16x8*)&Wt[w * 16 + arow][kt * 32 + koff];
    acc = __builtin_amdgcn_mfma_f32_16x16x32_bf16(av, bv, acc, 0, 0, 0);
  }
  // epilogue: lane holds rows {(l>>4)*4+q} x col (l&15) of head w's tile
  int col = l & 15;
  int rgrp = l >> 4;
  float as_ = att_src[w * NC + col], ad_ = att_dst[w * NC + col];
#pragma unroll
  for (int q = 0; q < 4; ++q) {
    int gr = row0 + rgrp * 4 + q;
    float v = acc[q];
    xwb[(size_t)gr * HC + w * 16 + col] = f2bf(v);
    float ps = v * as_, pd = v * ad_;
#pragma unroll
    for (int off = 8; off >= 1; off >>= 1) {
      ps += __shfl_xor(ps, off, 64);
      pd += __shfl_xor(pd, off, 64);
    }
    if (col == 0) {
      a_src[gr * NH + w] = ps;
      a_dst[gr * NH + w] = pd;
    }
  }
}

// one wave per destination node, single sweep over the dst's slot run
// (contiguous at d*CAP); alpha recomputed from L2-resident a_src (minimal
// VGPR, max occupancy — measured optimum among 8 structural variants).
// Overflow list replayed at the end. XCD-affine mapping.
// Lane layout head-major: lane j = head (j>>4) x slot (j&15).
__global__ __launch_bounds__(256) void k_gat(
    const int* __restrict__ cnt, const ushort* __restrict__ ss_slot,
    const int* __restrict__ ofcnt, const unsigned* __restrict__ of,
    const float* __restrict__ a_src, const float* __restrict__ a_dst,
    const ushort* __restrict__ xwb, const float* __restrict__ bias,
    float* __restrict__ out) {
  int tid = threadIdx.x;
  int wv = tid >> 6, j = tid & 63;
  int p = blockIdx.x & (NPART - 1);
  int idx = blockIdx.x >> 3;  // 0..GPB-1
  int dd = idx * 4 + wv;
  if (dd >= DPP) return;      // tail block: 2 idle waves
  int d = p * DPP + dd;
  int h = j >> 4, sl = j & 15;
  int base = d * CAP;
  int deg = min(cnt[d], CAP);  // cnt may exceed CAP (overflowed arrivals)

  float adr = a_dst[(size_t)d * NH + h];
  float ws = lrelu_exp(a_src[(size_t)d * NH + h] + adr);  // self score
  float lsum = (sl == 0) ? ws : 0.f;           // per-lane partial denominator
  float acc = ws * bf2f(xwb[(size_t)d * HC + j]);  // self contribution

  for (int i0 = 0; i0 < deg; i0 += 16) {
    int nb = min(16, deg - i0);
    int s_j = 0;
    float al = 0.f;
    if (sl < nb) {
      s_j = (int)ss_slot[base + i0 + sl];                  // coalesced 2B
      al = lrelu_exp(a_src[(size_t)s_j * NH + h] + adr);   // L2-resident gather
    }
    lsum += al;
    if (nb == 16) {
#pragma unroll
      for (int k = 0; k < 16; ++k) {
        int s = __builtin_amdgcn_readlane(s_j, k);  // lane k holds slot k
        float alpha = __shfl(al, k, 16);
        acc += alpha * bf2f(xwb[(size_t)s * HC + j]);
      }
    } else {
      for (int k = 0; k < nb; ++k) {
        int s = __shfl(s_j, k, 16);
        float alpha = __shfl(al, k, 16);
        acc += alpha * bf2f(xwb[(size_t)s * HC + j]);
      }
    }
  }
  // overflow replay (tiny; all-lane cached reads, match on d, recompute alpha)
  int oc = min(*ofcnt, OFCAP);
  for (int e = 0; e < oc; ++e) {
    unsigned r = of[e];
    if ((int)(r >> 16) == d) {
      int s = (int)(r & 0xFFFFu);
      float al = lrelu_exp(a_src[(size_t)s * NH + h] + adr);
      if (sl == 0) lsum += al;
      acc += al * bf2f(xwb[(size_t)s * HC + j]);
    }
  }
  float L = lsum;
#pragma unroll
  for (int off = 8; off >= 1; off >>= 1) L += __shfl_xor(L, off, 64);
  out[(size_t)d * HC + j] = acc / (L + 1e-16f) + bias[j];
}

extern "C" void kernel_launch(void* const* d_in, const int* in_sizes, int n_in,
                              void* d_out, int out_size, void* d_ws, size_t ws_size,
                              hipStream_t stream) {
  const float* x       = (const float*)d_in[0];
  const int*   ei      = (const int*)d_in[1];
  // d_in[2] = edge_attr: ignored by the reference layer
  const float* W       = (const float*)d_in[3];
  const float* att_src = (const float*)d_in[4];
  const float* att_dst = (const float*)d_in[5];
  const float* bias    = (const float*)d_in[6];
  float* out = (float*)d_out;

  char* p = (char*)d_ws;
  ushort*   xwb     = (ushort*)p;   p += (size_t)NN * HC * 2;    // 6.4 MB
  float*    a_src   = (float*)p;    p += (size_t)NN * NH * 4;    // 0.8 MB
  float*    a_dst   = (float*)p;    p += (size_t)NN * NH * 4;    // 0.8 MB
  int*      cnt     = (int*)p;      p += (size_t)NN * 4;         // 0.2 MB
  int*      ofcnt   = (int*)p;      p += 64;                     // 1 + pad
  ushort*   ss_slot = (ushort*)p;   p += (size_t)NN * CAP * 2;   // 3.2 MB
  unsigned* of      = (unsigned*)p; p += (size_t)OFCAP * 4;      // 32 KB

  hipMemsetAsync(cnt, 0, (size_t)NN * 4 + 64, stream);  // cnt + ofcnt
  k_fused<<<SBLK + XWB, 256, 0, stream>>>(x, W, att_src, att_dst,
                                          xwb, a_src, a_dst, cnt, ofcnt,
                                          ei, ss_slot, of);
  k_gat<<<NPART * GPB, 256, 0, stream>>>(cnt, ss_slot, ofcnt, of,
                                         a_src, a_dst, xwb, bias, out);
}

// Round 32
// 96.707 us; speedup vs baseline: 1.1472x; 1.0610x over previous
//
#include <hip/hip_runtime.h>

// GATConv: N=50000, NIN=128, H=4, C=16 (HC=64), E=800000 (+N self-loops,
// synthesized inside k_gat). Slot-table aggregation (no CSR).
// r32: k_fused with BRESENHAM-INTERLEAVED roles — r31 counters showed the
// 2048 scatter blocks filled the dispatch front (machine holds ~1792 blocks),
// so xw ran serially after scatter (53.5 = 45+8). Interleaving scatter/xw
// blocks 2:3 in dispatch order makes every CU co-host latency-bound scatter
// waves and MFMA xw waves (independent pipes overlap; m114).
// k_gat: one dst per wave, 16-lane-broadcast — optimum of 8 variants.
#define NN 50000
#define NIN 128
#define NH 4
#define NC 16
#define HC 64
#define NE 800000
#define NEG_SLOPE 0.2f
#define RPB 16                       // rows per block in xw path
#define XWB (NN / RPB)               // 3125 xw blocks
#define NPART 8                      // dst partitions (== XCD count)
#define SCHUNK 256                   // scatter-role blocks per partition
#define SBLK (NPART * SCHUNK)        // 2048 scatter-role blocks
#define TOTB (SBLK + XWB)            // 5173 total fused blocks
#define DPP (NN / NPART)             // 6250 dst per partition
#define GPB 1563                     // gat blocks per partition = ceil(6250/4)
#define CAP 32                       // slots per destination
#define OFCAP 8192                   // overflow list capacity (safety margin)

typedef __attribute__((ext_vector_type(8))) __bf16 bf16x8;
typedef __attribute__((ext_vector_type(4))) float f32x4;

__device__ __forceinline__ ushort f2bf(float v) {  // RNE f32->bf16
  unsigned u = __float_as_uint(v);
  return (ushort)((u + 0x7FFFu + ((u >> 16) & 1u)) >> 16);
}
__device__ __forceinline__ float bf2f(ushort b) {
  return __uint_as_float((unsigned)b << 16);
}
__device__ __forceinline__ float lrelu_exp(float e) {
  e = e > 0.f ? e : NEG_SLOPE * e;
  return __expf(fminf(e, 60.f));  // no max-shift needed: |e|<~12 on this data
}

// Fused producer kernel, interleaved roles. Role of block b (Bresenham):
// scatter iff floor((b+1)*SBLK/TOTB) > floor(b*SBLK/TOTB); scatter index =
// floor(b*SBLK/TOTB), xw index = b - that. Exactly SBLK scatter + XWB xw,
// both monotone, ~2:3 mixed throughout dispatch order -> true co-residency.
__global__ __launch_bounds__(256, 4) void k_fused(
    const float* __restrict__ x, const float* __restrict__ W,
    const float* __restrict__ att_src, const float* __restrict__ att_dst,
    ushort* __restrict__ xwb, float* __restrict__ a_src, float* __restrict__ a_dst,
    int* __restrict__ cnt, int* __restrict__ ofcnt,
    const int* __restrict__ ei,
    ushort* __restrict__ ss_slot, unsigned* __restrict__ of) {
  __shared__ ushort Wt[HC][NIN + 8];   // W transposed, bf16: 17.4 KB
  __shared__ ushort xs[RPB][NIN + 8];  // x tile, bf16: 4.4 KB
  int tid = threadIdx.x;
  unsigned b = blockIdx.x;
  unsigned sidx = (unsigned)(((unsigned long long)b * SBLK) / TOTB);
  unsigned snxt = (unsigned)(((unsigned long long)(b + 1) * SBLK) / TOTB);

  if (snxt > sidx) {
    // ---- scatter path (role index sidx in [0, SBLK); no LDS, no barriers) ----
    int p = sidx & (NPART - 1);
    int chunk = sidx >> 3;  // 0..SCHUNK-1
    int dlo = p * DPP, dhi = dlo + DPP;
    const int4* d4p = (const int4*)(ei + NE);
    const int ngroups = NE / 4;  // 200000
    for (int g = chunk * 256 + tid; g < ngroups; g += SCHUNK * 256) {
      int4 d4 = d4p[g];
#pragma unroll
      for (int c = 0; c < 4; ++c) {
        int d = (c == 0) ? d4.x : (c == 1) ? d4.y : (c == 2) ? d4.z : d4.w;
        if (d >= dlo && d < dhi) {
          int s = ei[g * 4 + c];  // lazy src load (L2/L3; hidden by atomic)
          int pos = atomicAdd(&cnt[d], 1);
          if (pos < CAP) {
            ss_slot[d * CAP + pos] = (ushort)s;
          } else {
            int op = atomicAdd(ofcnt, 1);
            if (op < OFCAP) of[op] = (unsigned)s | ((unsigned)d << 16);
          }
        }
      }
    }
    return;
  }

  // ---- xw path (role index b - sidx in [0, XWB)) ----
  int bid = (int)(b - sidx);
  int row0 = bid * RPB;  // NN % RPB == 0
  // stage W^T (coalesced global read, scattered 2B LDS writes, one-time)
  for (int i = tid; i < NIN * HC; i += 256) {
    int k = i >> 6, c = i & 63;
    Wt[c][k] = f2bf(W[i]);
  }
  // stage x tile: thread t converts 8 consecutive floats -> one b128 store
  {
    int f = tid * 8;  // 256*8 == 16*128
    int r = f >> 7, k = f & 127;
    const float4* xp = (const float4*)(x + (size_t)row0 * NIN + f);
    float4 v0 = xp[0], v1 = xp[1];
    union { bf16x8 v; ushort u[8]; } pkd;
    pkd.u[0] = f2bf(v0.x); pkd.u[1] = f2bf(v0.y);
    pkd.u[2] = f2bf(v0.z); pkd.u[3] = f2bf(v0.w);
    pkd.u[4] = f2bf(v1.x); pkd.u[5] = f2bf(v1.y);
    pkd.u[6] = f2bf(v1.z); pkd.u[7] = f2bf(v1.w);
    *(bf16x8*)&xs[r][k] = pkd.v;
  }
  __syncthreads();
  int l = tid & 63, w = tid >> 6;   // wave w == head w
  int arow = l & 15;                // A row / B col within tile
  int koff = (l >> 4) * 8;          // k sub-offset for A and B fragments
  f32x4 acc = {0.f, 0.f, 0.f, 0.f};
#pragma unroll
  for (int kt = 0; kt < 4; ++kt) {
    bf16x8 av = *(const bf16x8*)&xs[arow][kt * 32 + koff];
    bf16x8 bv = *(const bf16x8*)&Wt[w * 16 + arow][kt * 32 + koff];
    acc = __builtin_amdgcn_mfma_f32_16x16x32_bf16(av, bv, acc, 0, 0, 0);
  }
  // epilogue: lane holds rows {(l>>4)*4+q} x col (l&15) of head w's tile
  int col = l & 15;
  int rgrp = l >> 4;
  float as_ = att_src[w * NC + col], ad_ = att_dst[w * NC + col];
#pragma unroll
  for (int q = 0; q < 4; ++q) {
    int gr = row0 + rgrp * 4 + q;
    float v = acc[q];
    xwb[(size_t)gr * HC + w * 16 + col] = f2bf(v);
    float ps = v * as_, pd = v * ad_;
#pragma unroll
    for (int off = 8; off >= 1; off >>= 1) {
      ps += __shfl_xor(ps, off, 64);
      pd += __shfl_xor(pd, off, 64);
    }
    if (col == 0) {
      a_src[gr * NH + w] = ps;
      a_dst[gr * NH + w] = pd;
    }
  }
}

// one wave per destination node, single sweep over the dst's slot run
// (contiguous at d*CAP); alpha recomputed from L2-resident a_src (minimal
// VGPR, max occupancy — measured optimum among 8 structural variants).
// Overflow list replayed at the end. XCD-affine mapping.
// Lane layout head-major: lane j = head (j>>4) x slot (j&15).
__global__ __launch_bounds__(256) void k_gat(
    const int* __restrict__ cnt, const ushort* __restrict__ ss_slot,
    const int* __restrict__ ofcnt, const unsigned* __restrict__ of,
    const float* __restrict__ a_src, const float* __restrict__ a_dst,
    const ushort* __restrict__ xwb, const float* __restrict__ bias,
    float* __restrict__ out) {
  int tid = threadIdx.x;
  int wv = tid >> 6, j = tid & 63;
  int p = blockIdx.x & (NPART - 1);
  int idx = blockIdx.x >> 3;  // 0..GPB-1
  int dd = idx * 4 + wv;
  if (dd >= DPP) return;      // tail block: 2 idle waves
  int d = p * DPP + dd;
  int h = j >> 4, sl = j & 15;
  int base = d * CAP;
  int deg = min(cnt[d], CAP);  // cnt may exceed CAP (overflowed arrivals)

  float adr = a_dst[(size_t)d * NH + h];
  float ws = lrelu_exp(a_src[(size_t)d * NH + h] + adr);  // self score
  float lsum = (sl == 0) ? ws : 0.f;           // per-lane partial denominator
  float acc = ws * bf2f(xwb[(size_t)d * HC + j]);  // self contribution

  for (int i0 = 0; i0 < deg; i0 += 16) {
    int nb = min(16, deg - i0);
    int s_j = 0;
    float al = 0.f;
    if (sl < nb) {
      s_j = (int)ss_slot[base + i0 + sl];                  // coalesced 2B
      al = lrelu_exp(a_src[(size_t)s_j * NH + h] + adr);   // L2-resident gather
    }
    lsum += al;
    if (nb == 16) {
#pragma unroll
      for (int k = 0; k < 16; ++k) {
        int s = __builtin_amdgcn_readlane(s_j, k);  // lane k holds slot k
        float alpha = __shfl(al, k, 16);
        acc += alpha * bf2f(xwb[(size_t)s * HC + j]);
      }
    } else {
      for (int k = 0; k < nb; ++k) {
        int s = __shfl(s_j, k, 16);
        float alpha = __shfl(al, k, 16);
        acc += alpha * bf2f(xwb[(size_t)s * HC + j]);
      }
    }
  }
  // overflow replay (tiny; all-lane cached reads, match on d, recompute alpha)
  int oc = min(*ofcnt, OFCAP);
  for (int e = 0; e < oc; ++e) {
    unsigned r = of[e];
    if ((int)(r >> 16) == d) {
      int s = (int)(r & 0xFFFFu);
      float al = lrelu_exp(a_src[(size_t)s * NH + h] + adr);
      if (sl == 0) lsum += al;
      acc += al * bf2f(xwb[(size_t)s * HC + j]);
    }
  }
  float L = lsum;
#pragma unroll
  for (int off = 8; off >= 1; off >>= 1) L += __shfl_xor(L, off, 64);
  out[(size_t)d * HC + j] = acc / (L + 1e-16f) + bias[j];
}

extern "C" void kernel_launch(void* const* d_in, const int* in_sizes, int n_in,
                              void* d_out, int out_size, void* d_ws, size_t ws_size,
                              hipStream_t stream) {
  const float* x       = (const float*)d_in[0];
  const int*   ei      = (const int*)d_in[1];
  // d_in[2] = edge_attr: ignored by the reference layer
  const float* W       = (const float*)d_in[3];
  const float* att_src = (const float*)d_in[4];
  const float* att_dst = (const float*)d_in[5];
  const float* bias    = (const float*)d_in[6];
  float* out = (float*)d_out;

  char* p = (char*)d_ws;
  ushort*   xwb     = (ushort*)p;   p += (size_t)NN * HC * 2;    // 6.4 MB
  float*    a_src   = (float*)p;    p += (size_t)NN * NH * 4;    // 0.8 MB
  float*    a_dst   = (float*)p;    p += (size_t)NN * NH * 4;    // 0.8 MB
  int*      cnt     = (int*)p;      p += (size_t)NN * 4;         // 0.2 MB
  int*      ofcnt   = (int*)p;      p += 64;                     // 1 + pad
  ushort*   ss_slot = (ushort*)p;   p += (size_t)NN * CAP * 2;   // 3.2 MB
  unsigned* of      = (unsigned*)p; p += (size_t)OFCAP * 4;      // 32 KB

  hipMemsetAsync(cnt, 0, (size_t)NN * 4 + 64, stream);  // cnt + ofcnt
  k_fused<<<TOTB, 256, 0, stream>>>(x, W, att_src, att_dst,
                                    xwb, a_src, a_dst, cnt, ofcnt,
                                    ei, ss_slot, of);
  k_gat<<<NPART * GPB, 256, 0, stream>>>(cnt, ss_slot, ofcnt, of,
                                         a_src, a_dst, xwb, bias, out);
}

// Round 33
// 96.423 us; speedup vs baseline: 1.1505x; 1.0029x over previous
//
#include <hip/hip_runtime.h>

// GATConv: N=50000, NIN=128, H=4, C=16 (HC=64), E=800000 (+N self-loops,
// synthesized inside k_gat). Slot-table aggregation (no CSR).
// r33 = r32 (Bresenham-interleaved fused scatter+xw, wall 96.7) with the
// scatter role at SPART=4: interleaving already scrambled XCD affinity
// (sidx&7 != b%8) yet got FASTER -> affinity not binding; halving the
// d-stream re-read (25.6->12.8MB) now matters because scatter competes
// with xw's memory streams in the shared-residency regime.
// k_gat: one dst per wave, 16-lane-broadcast — optimum of 8 variants.
#define NN 50000
#define NIN 128
#define NH 4
#define NC 16
#define HC 64
#define NE 800000
#define NEG_SLOPE 0.2f
#define RPB 16                       // rows per block in xw path
#define XWB (NN / RPB)               // 3125 xw blocks
#define NPART 8                      // dst partitions for k_gat mapping
#define SPART 4                      // dst partitions for scatter role
#define SCHUNK 512                   // scatter-role blocks per partition
#define SBLK (SPART * SCHUNK)        // 2048 scatter-role blocks
#define TOTB (SBLK + XWB)            // 5173 total fused blocks
#define DPP (NN / NPART)             // 6250 dst per gat partition
#define SDPP (NN / SPART)            // 12500 dst per scatter partition
#define GPB 1563                     // gat blocks per partition = ceil(6250/4)
#define CAP 32                       // slots per destination
#define OFCAP 8192                   // overflow list capacity (safety margin)

typedef __attribute__((ext_vector_type(8))) __bf16 bf16x8;
typedef __attribute__((ext_vector_type(4))) float f32x4;

__device__ __forceinline__ ushort f2bf(float v) {  // RNE f32->bf16
  unsigned u = __float_as_uint(v);
  return (ushort)((u + 0x7FFFu + ((u >> 16) & 1u)) >> 16);
}
__device__ __forceinline__ float bf2f(ushort b) {
  return __uint_as_float((unsigned)b << 16);
}
__device__ __forceinline__ float lrelu_exp(float e) {
  e = e > 0.f ? e : NEG_SLOPE * e;
  return __expf(fminf(e, 60.f));  // no max-shift needed: |e|<~12 on this data
}

// Fused producer kernel, interleaved roles. Role of block b (Bresenham):
// scatter iff floor((b+1)*SBLK/TOTB) > floor(b*SBLK/TOTB); scatter index =
// floor(b*SBLK/TOTB), xw index = b - that. Exactly SBLK scatter + XWB xw,
// both monotone, ~2:3 mixed throughout dispatch order -> true co-residency.
__global__ __launch_bounds__(256, 4) void k_fused(
    const float* __restrict__ x, const float* __restrict__ W,
    const float* __restrict__ att_src, const float* __restrict__ att_dst,
    ushort* __restrict__ xwb, float* __restrict__ a_src, float* __restrict__ a_dst,
    int* __restrict__ cnt, int* __restrict__ ofcnt,
    const int* __restrict__ ei,
    ushort* __restrict__ ss_slot, unsigned* __restrict__ of) {
  __shared__ ushort Wt[HC][NIN + 8];   // W transposed, bf16: 17.4 KB
  __shared__ ushort xs[RPB][NIN + 8];  // x tile, bf16: 4.4 KB
  int tid = threadIdx.x;
  unsigned b = blockIdx.x;
  unsigned sidx = (unsigned)(((unsigned long long)b * SBLK) / TOTB);
  unsigned snxt = (unsigned)(((unsigned long long)(b + 1) * SBLK) / TOTB);

  if (snxt > sidx) {
    // ---- scatter path (role index sidx in [0, SBLK); no LDS, no barriers) ----
    int p = sidx & (SPART - 1);
    int chunk = sidx >> 2;  // 0..SCHUNK-1
    int dlo = p * SDPP, dhi = dlo + SDPP;
    const int4* d4p = (const int4*)(ei + NE);
    const int ngroups = NE / 4;  // 200000
    for (int g = chunk * 256 + tid; g < ngroups; g += SCHUNK * 256) {
      int4 d4 = d4p[g];
#pragma unroll
      for (int c = 0; c < 4; ++c) {
        int d = (c == 0) ? d4.x : (c == 1) ? d4.y : (c == 2) ? d4.z : d4.w;
        if (d >= dlo && d < dhi) {
          int s = ei[g * 4 + c];  // lazy src load (L2/L3; hidden by atomic)
          int pos = atomicAdd(&cnt[d], 1);
          if (pos < CAP) {
            ss_slot[d * CAP + pos] = (ushort)s;
          } else {
            int op = atomicAdd(ofcnt, 1);
            if (op < OFCAP) of[op] = (unsigned)s | ((unsigned)d << 16);
          }
        }
      }
    }
    return;
  }

  // ---- xw path (role index b - sidx in [0, XWB)) ----
  int bid = (int)(b - sidx);
  int row0 = bid * RPB;  // NN % RPB == 0
  // stage W^T (coalesced global read, scattered 2B LDS writes, one-time)
  for (int i = tid; i < NIN * HC; i += 256) {
    int k = i >> 6, c = i & 63;
    Wt[c][k] = f2bf(W[i]);
  }
  // stage x tile: thread t converts 8 consecutive floats -> one b128 store
  {
    int f = tid * 8;  // 256*8 == 16*128
    int r = f >> 7, k = f & 127;
    const float4* xp = (const float4*)(x + (size_t)row0 * NIN + f);
    float4 v0 = xp[0], v1 = xp[1];
    union { bf16x8 v; ushort u[8]; } pkd;
    pkd.u[0] = f2bf(v0.x); pkd.u[1] = f2bf(v0.y);
    pkd.u[2] = f2bf(v0.z); pkd.u[3] = f2bf(v0.w);
    pkd.u[4] = f2bf(v1.x); pkd.u[5] = f2bf(v1.y);
    pkd.u[6] = f2bf(v1.z); pkd.u[7] = f2bf(v1.w);
    *(bf16x8*)&xs[r][k] = pkd.v;
  }
  __syncthreads();
  int l = tid & 63, w = tid >> 6;   // wave w == head w
  int arow = l & 15;                // A row / B col within tile
  int koff = (l >> 4) * 8;          // k sub-offset for A and B fragments
  f32x4 acc = {0.f, 0.f, 0.f, 0.f};
#pragma unroll
  for (int kt = 0; kt < 4; ++kt) {
    bf16x8 av = *(const bf16x8*)&xs[arow][kt * 32 + koff];
    bf16x8 bv = *(const bf16x8*)&Wt[w * 16 + arow][kt * 32 + koff];
    acc = __builtin_amdgcn_mfma_f32_16x16x32_bf16(av, bv, acc, 0, 0, 0);
  }
  // epilogue: lane holds rows {(l>>4)*4+q} x col (l&15) of head w's tile
  int col = l & 15;
  int rgrp = l >> 4;
  float as_ = att_src[w * NC + col], ad_ = att_dst[w * NC + col];
#pragma unroll
  for (int q = 0; q < 4; ++q) {
    int gr = row0 + rgrp * 4 + q;
    float v = acc[q];
    xwb[(size_t)gr * HC + w * 16 + col] = f2bf(v);
    float ps = v * as_, pd = v * ad_;
#pragma unroll
    for (int off = 8; off >= 1; off >>= 1) {
      ps += __shfl_xor(ps, off, 64);
      pd += __shfl_xor(pd, off, 64);
    }
    if (col == 0) {
      a_src[gr * NH + w] = ps;
      a_dst[gr * NH + w] = pd;
    }
  }
}

// one wave per destination node, single sweep over the dst's slot run
// (contiguous at d*CAP); alpha recomputed from L2-resident a_src (minimal
// VGPR, max occupancy — measured optimum among 8 structural variants).
// Overflow list replayed at the end. XCD-affine mapping.
// Lane layout head-major: lane j = head (j>>4) x slot (j&15).
__global__ __launch_bounds__(256) void k_gat(
    const int* __restrict__ cnt, const ushort* __restrict__ ss_slot,
    const int* __restrict__ ofcnt, const unsigned* __restrict__ of,
    const float* __restrict__ a_src, const float* __restrict__ a_dst,
    const ushort* __restrict__ xwb, const float* __restrict__ bias,
    float* __restrict__ out) {
  int tid = threadIdx.x;
  int wv = tid >> 6, j = tid & 63;
  int p = blockIdx.x & (NPART - 1);
  int idx = blockIdx.x >> 3;  // 0..GPB-1
  int dd = idx * 4 + wv;
  if (dd >= DPP) return;      // tail block: 2 idle waves
  int d = p * DPP + dd;
  int h = j >> 4, sl = j & 15;
  int base = d * CAP;
  int deg = min(cnt[d], CAP);  // cnt may exceed CAP (overflowed arrivals)

  float adr = a_dst[(size_t)d * NH + h];
  float ws = lrelu_exp(a_src[(size_t)d * NH + h] + adr);  // self score
  float lsum = (sl == 0) ? ws : 0.f;           // per-lane partial denominator
  float acc = ws * bf2f(xwb[(size_t)d * HC + j]);  // self contribution

  for (int i0 = 0; i0 < deg; i0 += 16) {
    int nb = min(16, deg - i0);
    int s_j = 0;
    float al = 0.f;
    if (sl < nb) {
      s_j = (int)ss_slot[base + i0 + sl];                  // coalesced 2B
      al = lrelu_exp(a_src[(size_t)s_j * NH + h] + adr);   // L2-resident gather
    }
    lsum += al;
    if (nb == 16) {
#pragma unroll
      for (int k = 0; k < 16; ++k) {
        int s = __builtin_amdgcn_readlane(s_j, k);  // lane k holds slot k
        float alpha = __shfl(al, k, 16);
        acc += alpha * bf2f(xwb[(size_t)s * HC + j]);
      }
    } else {
      for (int k = 0; k < nb; ++k) {
        int s = __shfl(s_j, k, 16);
        float alpha = __shfl(al, k, 16);
        acc += alpha * bf2f(xwb[(size_t)s * HC + j]);
      }
    }
  }
  // overflow replay (tiny; all-lane cached reads, match on d, recompute alpha)
  int oc = min(*ofcnt, OFCAP);
  for (int e = 0; e < oc; ++e) {
    unsigned r = of[e];
    if ((int)(r >> 16) == d) {
      int s = (int)(r & 0xFFFFu);
      float al = lrelu_exp(a_src[(size_t)s * NH + h] + adr);
      if (sl == 0) lsum += al;
      acc += al * bf2f(xwb[(size_t)s * HC + j]);
    }
  }
  float L = lsum;
#pragma unroll
  for (int off = 8; off >= 1; off >>= 1) L += __shfl_xor(L, off, 64);
  out[(size_t)d * HC + j] = acc / (L + 1e-16f) + bias[j];
}

extern "C" void kernel_launch(void* const* d_in, const int* in_sizes, int n_in,
                              void* d_out, int out_size, void* d_ws, size_t ws_size,
                              hipStream_t stream) {
  const float* x       = (const float*)d_in[0];
  const int*   ei      = (const int*)d_in[1];
  // d_in[2] = edge_attr: ignored by the reference layer
  const float* W       = (const float*)d_in[3];
  const float* att_src = (const float*)d_in[4];
  const float* att_dst = (const float*)d_in[5];
  const float* bias    = (const float*)d_in[6];
  float* out = (float*)d_out;

  char* p = (char*)d_ws;
  ushort*   xwb     = (ushort*)p;   p += (size_t)NN * HC * 2;    // 6.4 MB
  float*    a_src   = (float*)p;    p += (size_t)NN * NH * 4;    // 0.8 MB
  float*    a_dst   = (float*)p;    p += (size_t)NN * NH * 4;    // 0.8 MB
  int*      cnt     = (int*)p;      p += (size_t)NN * 4;         // 0.2 MB
  int*      ofcnt   = (int*)p;      p += 64;                     // 1 + pad
  ushort*   ss_slot = (ushort*)p;   p += (size_t)NN * CAP * 2;   // 3.2 MB
  unsigned* of      = (unsigned*)p; p += (size_t)OFCAP * 4;      // 32 KB

  hipMemsetAsync(cnt, 0, (size_t)NN * 4 + 64, stream);  // cnt + ofcnt
  k_fused<<<TOTB, 256, 0, stream>>>(x, W, att_src, att_dst,
                                    xwb, a_src, a_dst, cnt, ofcnt,
                                    ei, ss_slot, of);
  k_gat<<<NPART * GPB, 256, 0, stream>>>(cnt, ss_slot, ofcnt, of,
                                         a_src, a_dst, xwb, bias, out);
}